// Round 8
// baseline (40.344 us; speedup 1.0000x reference)
//
#include <hip/hip_runtime.h>
#include <hip/hip_bf16.h>

// RGCN fused: out = relu( [x | agg_r0..agg_r15] @ [w_self | w_rel]^T )
// B=4096, S=10, R=16, F=128, K_total=2176.
// v8: v6 structure VERBATIM (barriers, phases A0/A/C/D) made single-kernel:
// phase B streams W as fp32 directly from w_self/w_rel and converts inline
// (v_cvt_pk_bf16_f32). No carried W pipeline (v7's suspect), no tail
// prefetch. Step-0 W prefetched at kernel top to start the L2 stream early.

#define BT   16
#define LDA  2184            // bf16 elems per A_t row (2176 + 8 pad)
#define NTHR 1024

typedef __attribute__((ext_vector_type(8))) short short8;  // 8 bf16
typedef __attribute__((ext_vector_type(4))) float f32x4;   // MFMA acc

__device__ __forceinline__ unsigned int pk2_rne(float lo, float hi) {
  unsigned int r;
  asm("v_cvt_pk_bf16_f32 %0, %1, %2" : "=v"(r) : "v"(lo), "v"(hi));
  return r;
}

// Workgroup barrier draining LDS ops only — global loads stay in flight.
__device__ __forceinline__ void barrier_lgkm() {
  __builtin_amdgcn_sched_barrier(0);
  asm volatile("s_waitcnt lgkmcnt(0)" ::: "memory");
  __builtin_amdgcn_s_barrier();
  __builtin_amdgcn_sched_barrier(0);
}

__global__ __launch_bounds__(NTHR)
void rgcn_fused(const float* __restrict__ emb,
                const float* __restrict__ w_self,
                const float* __restrict__ w_rel,
                const int*   __restrict__ nodes,
                const int*   __restrict__ neighbors,
                const int*   __restrict__ rel_mask,
                float*       __restrict__ out)
{
  __shared__ alignas(16) char smem[80128];
  unsigned short* A_t = (unsigned short*)smem;                  // [16][2184] bf16
  float* P = (float*)smem;                                      // P0 [16][132]; P1 at +2112 words
  float (*mscale)[10][16] = (float (*)[10][16])(smem + 69888);  // [16][10][16]

  const int t  = threadIdx.x;
  const int l  = t & 63;
  const int w  = t >> 6;           // wave 0..15
  const int b0 = blockIdx.x * BT;

  // phase-B identity: wave = (o-group of 2 tiles) x (k-quarter of 17 ks)
  const int og  = w & 3,  kq = w >> 2;
  const int ot0 = og * 2;
  const int ksq = kq * 17;
  const int ln  = l & 15, lj = l >> 4;
  const int o0c = ot0 * 16 + ln;   // output cols this lane covers
  const int o1c = o0c + 16;

  // ---------- index loads (first: gathers depend on them) ----------
  const int bi   = w;              // node slot 0..15 (one per wave)
  const int b    = b0 + bi;
  const int node = nodes[b];
  int nb[10];
  {
    const int2* np = (const int2*)(neighbors + (size_t)b * 10);  // 8B-aligned (40B stride)
    const int2 p0 = np[0], p1 = np[1], p2 = np[2], p3 = np[3], p4 = np[4];
    nb[0]=p0.x; nb[1]=p0.y; nb[2]=p1.x; nb[3]=p1.y; nb[4]=p2.x;
    nb[5]=p2.y; nb[6]=p3.x; nb[7]=p3.y; nb[8]=p4.x; nb[9]=p4.y;
  }

  // ---------- mask loads (waves 0-3 cover 16 nodes x 16 relations) ----------
  int mb[10];
  if (t < 256) {
    const int* mp = rel_mask + (size_t)(b0 + (t >> 4)) * 160 + (t & 15);
    #pragma unroll
    for (int s = 0; s < 10; ++s) mb[s] = mp[s * 16];
  }

  // ---------- W step-0 prefetch (independent; starts the L2 stream now) ----------
  float4 W0a, W0b, W1a, W1b;
  {
    const int k0 = ksq * 32 + lj * 8;
    const float *p0, *p1;
    if (k0 < 128) {
      p0 = w_self + o0c * 128 + k0;
      p1 = w_self + o1c * 128 + k0;
    } else {
      const int r = (k0 - 128) >> 7, kc = (k0 - 128) & 127;
      p0 = w_rel + (size_t)r * 16384 + o0c * 128 + kc;
      p1 = w_rel + (size_t)r * 16384 + o1c * 128 + kc;
    }
    W0a = *(const float4*)p0; W0b = *(const float4*)(p0 + 4);
    W1a = *(const float4*)p1; W1b = *(const float4*)(p1 + 4);
  }

  // ---------- gathers (issued early; consumed in phase A) ----------
  const int f0 = l * 2;            // 2 features per lane
  float2 ne[10];
  #pragma unroll
  for (int s = 0; s < 10; ++s)
    ne[s] = *(const float2*)(emb + (size_t)nb[s] * 128 + f0);
  const float2 x2 = *(const float2*)(emb + (size_t)node * 128 + f0);

  // ---------- mscale[b][s][r] = m/(count+eps) ----------
  if (t < 256) {
    int c = 0;
    #pragma unroll
    for (int s = 0; s < 10; ++s) c += mb[s];
    const float inv = 1.0f / ((float)c + 1e-10f);
    #pragma unroll
    for (int s = 0; s < 10; ++s) mscale[t >> 4][s][t & 15] = mb[s] ? inv : 0.0f;
  }
  barrier_lgkm();

  // ---------- Phase A: wave w builds A_t row w (self + 16 masked means) ----------
  {
    char* arow = (char*)A_t + bi * (LDA * 2);
    *(unsigned int*)(arow + f0 * 2) = pk2_rne(x2.x, x2.y);     // self, k in [0,128)
    float acc[16][2];
    #pragma unroll
    for (int r = 0; r < 16; ++r) { acc[r][0] = 0.f; acc[r][1] = 0.f; }
    #pragma unroll
    for (int s = 0; s < 10; ++s) {
      const float4 m0 = *(const float4*)(&mscale[bi][s][0]);   // uniform -> LDS broadcast
      const float4 m1 = *(const float4*)(&mscale[bi][s][4]);
      const float4 m2 = *(const float4*)(&mscale[bi][s][8]);
      const float4 m3 = *(const float4*)(&mscale[bi][s][12]);
      const float m[16] = {m0.x,m0.y,m0.z,m0.w, m1.x,m1.y,m1.z,m1.w,
                           m2.x,m2.y,m2.z,m2.w, m3.x,m3.y,m3.z,m3.w};
      const float2 v = ne[s];
      #pragma unroll
      for (int r = 0; r < 16; ++r) {
        acc[r][0] += m[r] * v.x;
        acc[r][1] += m[r] * v.y;
      }
    }
    #pragma unroll
    for (int r = 0; r < 16; ++r)                               // rel r: k in [128+128r, ...)
      *(unsigned int*)(arow + 256 + r * 256 + f0 * 2) = pk2_rne(acc[r][0], acc[r][1]);
  }
  barrier_lgkm();

  // ---------- Phase B: 17 k-steps x 2 o-tiles; fp32 W loaded + cvt inline ----------
  f32x4 accA = {0.f,0.f,0.f,0.f}, accB = {0.f,0.f,0.f,0.f};
  {
    const char* ar = (const char*)A_t + ln * (LDA * 2) + lj * 16;
    #pragma unroll
    for (int i = 0; i < 17; ++i) {
      const int ks = ksq + i;
      float4 a0, a1, b0v, b1v;
      if (i == 0) {
        a0 = W0a; a1 = W0b; b0v = W1a; b1v = W1b;
      } else {
        const int k0 = ks * 32 + lj * 8;
        const float *p0, *p1;
        if (k0 < 128) {
          p0 = w_self + o0c * 128 + k0;
          p1 = w_self + o1c * 128 + k0;
        } else {
          const int r = (k0 - 128) >> 7, kc = (k0 - 128) & 127;
          p0 = w_rel + (size_t)r * 16384 + o0c * 128 + kc;
          p1 = w_rel + (size_t)r * 16384 + o1c * 128 + kc;
        }
        a0  = *(const float4*)p0; a1  = *(const float4*)(p0 + 4);
        b0v = *(const float4*)p1; b1v = *(const float4*)(p1 + 4);
      }
      const short8 a = *(const short8*)(ar + ks * 64);         // one read, two MFMAs
      union { unsigned int u[4]; short8 s; } u0, u1;
      u0.u[0] = pk2_rne(a0.x, a0.y);   u0.u[1] = pk2_rne(a0.z, a0.w);
      u0.u[2] = pk2_rne(a1.x, a1.y);   u0.u[3] = pk2_rne(a1.z, a1.w);
      u1.u[0] = pk2_rne(b0v.x, b0v.y); u1.u[1] = pk2_rne(b0v.z, b0v.w);
      u1.u[2] = pk2_rne(b1v.x, b1v.y); u1.u[3] = pk2_rne(b1v.z, b1v.w);
      accA = __builtin_amdgcn_mfma_f32_16x16x32_bf16(a, u0.s, accA, 0, 0, 0);
      accB = __builtin_amdgcn_mfma_f32_16x16x32_bf16(a, u1.s, accB, 0, 0, 0);
    }
  }
  barrier_lgkm();                  // A_t dead; P0/P1 alias it

  // ---------- Phase C: kq even writes, kq odd accumulates (v6 verbatim) ----------
  {
    float* Pg = P + (kq >> 1) * 2112;          // kq 0,1 -> P0 ; kq 2,3 -> P1
    if ((kq & 1) == 0) {
      #pragma unroll
      for (int j = 0; j < 4; ++j) {
        Pg[(lj*4+j)*132 + o0c] = accA[j];
        Pg[(lj*4+j)*132 + o1c] = accB[j];
      }
    }
    barrier_lgkm();
    if ((kq & 1) == 1) {
      #pragma unroll
      for (int j = 0; j < 4; ++j) {
        Pg[(lj*4+j)*132 + o0c] += accA[j];
        Pg[(lj*4+j)*132 + o1c] += accB[j];
      }
    }
    barrier_lgkm();
  }

  // ---------- Phase D: out = relu(P0 + P1) (v6 verbatim) ----------
  {
    const int row = w;
    const int cc  = l * 2;
    const float2 pa = *(const float2*)(P + row * 132 + cc);
    const float2 pb = *(const float2*)(P + 2112 + row * 132 + cc);
    float2 o2;
    o2.x = fmaxf(pa.x + pb.x, 0.f);
    o2.y = fmaxf(pa.y + pb.y, 0.f);
    *(float2*)(out + (size_t)(b0 + row) * 128 + cc) = o2;
  }
}

extern "C" void kernel_launch(void* const* d_in, const int* in_sizes, int n_in,
                              void* d_out, int out_size, void* d_ws, size_t ws_size,
                              hipStream_t stream) {
  const float* emb       = (const float*)d_in[0];
  const float* w_self    = (const float*)d_in[1];
  const float* w_rel     = (const float*)d_in[2];
  const int*   nodes     = (const int*)d_in[3];
  const int*   neighbors = (const int*)d_in[4];
  const int*   rel_mask  = (const int*)d_in[5];
  float* out = (float*)d_out;
  (void)in_sizes; (void)n_in; (void)out_size; (void)d_ws; (void)ws_size;

  rgcn_fused<<<4096 / BT, NTHR, 0, stream>>>(
      emb, w_self, w_rel, nodes, neighbors, rel_mask, out);
}